// Round 4
// baseline (6180.279 us; speedup 1.0000x reference)
//
#include <hip/hip_runtime.h>
#include <math.h>

// ---------------- problem constants ----------------
namespace {
constexpr int NB = 4;
constexpr int SEQ = 128;
constexpr int TH_ = 120;
constexpr int NSTEP = 8;
constexpr int DMODEL = 512;
constexpr int NHEAD = 8;
constexpr int DHEAD = 64;
constexpr int DFFN = 2048;
constexpr int DIN = 32;
constexpr int MROWS = NB*SEQ;   // 512
constexpr float SCALE_EMB = 22.627416997969522f; // sqrt(512)
constexpr float LN_EPS = 1e-5f;
constexpr float NEGF = -3.4028234663852886e38f;  // jnp.finfo(f32).min
constexpr float PE_C = -0.017988946039015984f;   // -ln(10000)/512
constexpr int NWG = 256;        // persistent grid = #CUs (co-residency guaranteed)
}

using short8 = __attribute__((ext_vector_type(8))) short;
using f32x4  = __attribute__((ext_vector_type(4))) float;

// ---------------- device helpers ----------------
__device__ __forceinline__ float wave_sum(float v){
#pragma unroll
  for(int off=32;off;off>>=1) v += __shfl_xor(v,off,64);
  return v;
}
__device__ __forceinline__ float gelu_t(float x){
  float t = 0.7978845608028654f*(x + 0.044715f*x*x*x);
  return 0.5f*x*(1.0f + tanhf(t));
}
__device__ __forceinline__ float pe_val(int t, int d){
  float div = expf((float)(d & ~1) * PE_C);
  float a = (float)t * div;
  return (d & 1) ? cosf(a) : sinf(a);
}
__device__ __forceinline__ unsigned short f2b(float f){
  union { float f; unsigned u; } c; c.f = f;
  unsigned u = c.u + 0x7FFFu + ((c.u>>16)&1u);
  return (unsigned short)(u>>16);
}
__device__ __forceinline__ short8 pack8(const float* f){
  short8 s;
#pragma unroll
  for(int i=0;i<8;i++) s[i] = (short)f2b(f[i]);
  return s;
}

// ---------------- shared-memory union ----------------
union SMem {
  struct {                                  // GEMM stage: 23.3 KB
    unsigned short As[32][72];
    unsigned short Bs[128][72];
    float mu[32], rs[32];
  } g;
  struct {                                  // attention: 58.4 KB (max)
    float kv[SEQ][DHEAD];
    float wsm[32][132];
    float qs[32][68];
  } a;
  struct {                                  // ctx: 4.1 KB
    float raw[DMODEL]; float ctx[DMODEL]; float scr[4];
  } c;
  struct {                                  // refine: 8.3 KB
    float cur[DIN]; float dscr[DIN]; float gs[DFFN];
  } r;
};

// ---------------- grid barrier (sense-reversing, device scope) ----------------
__device__ __forceinline__ void gbar(unsigned* cnt, unsigned* gen){
  __syncthreads();
  if(threadIdx.x==0){
    unsigned g = __hip_atomic_load(gen, __ATOMIC_RELAXED, __HIP_MEMORY_SCOPE_AGENT);
    __threadfence();   // release: wb local L2 (covers whole wg's stores post-syncthreads)
    if(__hip_atomic_fetch_add(cnt, 1u, __ATOMIC_RELAXED, __HIP_MEMORY_SCOPE_AGENT) == NWG-1u){
      __hip_atomic_store(cnt, 0u, __ATOMIC_RELAXED, __HIP_MEMORY_SCOPE_AGENT);
      __hip_atomic_fetch_add(gen, 1u, __ATOMIC_RELEASE, __HIP_MEMORY_SCOPE_AGENT);
    } else {
      while(__hip_atomic_load(gen, __ATOMIC_RELAXED, __HIP_MEMORY_SCOPE_AGENT) == g)
        __builtin_amdgcn_s_sleep(2);
    }
    __threadfence();   // acquire: inv L1/L2
  }
  __syncthreads();
}

// ---------------- init kernels (3 small dispatches) ----------------
__global__ __launch_bounds__(256) void conv_w(const float* __restrict__ Wq,
                                              const float* __restrict__ Wk,
                                              const float* __restrict__ Wv,
                                              const float* __restrict__ Wo,
                                              const float* __restrict__ W1,
                                              const float* __restrict__ W2,
                                              unsigned short* __restrict__ dst){
  size_t base = ((size_t)blockIdx.x*256 + threadIdx.x)*8;
  if(base >= 12582912u) return;
  const float* src; size_t off;
  if(base < 1048576u){ src=Wq; off=base; }
  else if(base < 2097152u){ src=Wk; off=base-1048576u; }
  else if(base < 3145728u){ src=Wv; off=base-2097152u; }
  else if(base < 4194304u){ src=Wo; off=base-3145728u; }
  else if(base < 8388608u){ src=W1; off=base-4194304u; }
  else { src=W2; off=base-8388608u; }
  float4 a = *(const float4*)(src+off);
  float4 b = *(const float4*)(src+off+4);
  float f[8] = {a.x,a.y,a.z,a.w,b.x,b.y,b.z,b.w};
  *(short8*)(dst + base) = pack8(f);
}

__global__ __launch_bounds__(256) void init_h0(const float* __restrict__ hist,
                                               const float* __restrict__ W_emb,
                                               const float* __restrict__ b_emb,
                                               float* __restrict__ h0,
                                               unsigned short* __restrict__ h0b){
  int bt = blockIdx.x;
  int b = bt >> 7, t = bt & 127;
  __shared__ float x[DIN];
  if(threadIdx.x < DIN)
    x[threadIdx.x] = (t < TH_) ? hist[((size_t)b*TH_ + t)*DIN + threadIdx.x] : 0.f;
  __syncthreads();
  for(int d = threadIdx.x; d < DMODEL; d += 256){
    float s = 0.f;
#pragma unroll 8
    for(int i=0;i<DIN;i++) s += W_emb[d*DIN+i]*x[i];
    float v = SCALE_EMB*(s + b_emb[d]) + pe_val(t,d);
    h0[(size_t)bt*DMODEL + d] = v;
    h0b[(size_t)bt*DMODEL + d] = f2b(v);
  }
}

__global__ __launch_bounds__(256) void init_misc(const float* __restrict__ Wr1,
                                                 const float* __restrict__ W_emb,
                                                 const float* __restrict__ b_emb,
                                                 const float* __restrict__ br1,
                                                 const float* __restrict__ hist,
                                                 float* __restrict__ M1,
                                                 float* __restrict__ cb1,
                                                 float* __restrict__ cur_x){
  __shared__ float row[DMODEL];
  int j0 = blockIdx.x*8;
  for(int jj=0;jj<8;jj++){
    int j = j0+jj;
    for(int k=threadIdx.x;k<DMODEL;k+=256) row[k] = Wr1[(size_t)j*1024 + k];
    __syncthreads();
    if(threadIdx.x < DIN){
      int i = threadIdx.x; float s = 0.f;
      for(int k=0;k<DMODEL;k++) s += row[k]*W_emb[k*DIN+i];
      M1[j*DIN+i] = SCALE_EMB*s;
    } else if(threadIdx.x == DIN){
      float s=0.f;
      for(int k=0;k<DMODEL;k++) s += row[k]*b_emb[k];
      cb1[j] = br1[j] + SCALE_EMB*s;
    }
    __syncthreads();
  }
  if(blockIdx.x==0 && threadIdx.x<NB*DIN){
    int b = threadIdx.x>>5, i = threadIdx.x&31;
    cur_x[b*DIN+i] = hist[((size_t)b*TH_ + (TH_-1))*DIN + i];
  }
}

// ---------------- GEMM stage (device fn): 32x128 tiles, bf16 MFMA ----------------
// amode: A16 != nullptr -> bf16 A; else fp32 Afp with LN prologue (Ka==512),
//        nt==0 tiles write LN'd fp32 rows to lnout.
// cmode: 0 fp32 out; 1 bf16 out; 2 fused-QKV scatter.
__device__ void gemm_stage(
    int ntN,
    const unsigned short* A16,
    const float* Afp, const float* lng, const float* lnb, float* lnout,
    int Ka,
    const unsigned short* W0, const unsigned short* W1w, const unsigned short* W2w,
    const float* bias, const float* resid,
    float* Cf, unsigned short* Cb, int c_rs, int cmode, int act,
    SMem& sm)
{
  int tid = threadIdx.x, w = tid>>6, l = tid&63;
  int ntiles = 16*ntN;
  int fr = l&15, fq = (l>>4)*8;
  int ar = tid>>3, akq = (tid&7)*8;
  int br_ = tid>>1, bkq = (tid&1)*32;

  for(int tile=blockIdx.x; tile<ntiles; tile+=NWG){
    int mt = tile/ntN, nt = tile - mt*ntN;
    int m0 = mt*32, n0 = nt*128;
    const unsigned short* Wsrc; int nr0;
    if(cmode==2){ int which = n0>>9; Wsrc = (which==0?W0:(which==1?W1w:W2w)); nr0 = n0&511; }
    else { Wsrc = W0; nr0 = n0; }

    if(Afp){ // LN prologue: 4 waves x 8 rows
      for(int r8=0;r8<8;r8++){
        int r = w*8 + r8;
        const float* ap = Afp + (size_t)(m0+r)*Ka + l*8;
        float4 x0 = *(const float4*)ap, x1 = *(const float4*)(ap+4);
        float s = x0.x+x0.y+x0.z+x0.w+x1.x+x1.y+x1.z+x1.w;
        s = wave_sum(s);
        float mu = s*(1.f/DMODEL);
        float v = (x0.x-mu)*(x0.x-mu)+(x0.y-mu)*(x0.y-mu)+(x0.z-mu)*(x0.z-mu)+(x0.w-mu)*(x0.w-mu)
                + (x1.x-mu)*(x1.x-mu)+(x1.y-mu)*(x1.y-mu)+(x1.z-mu)*(x1.z-mu)+(x1.w-mu)*(x1.w-mu);
        v = wave_sum(v);
        float rs = rsqrtf(v*(1.f/DMODEL) + LN_EPS);
        if(l==0){ sm.g.mu[r]=mu; sm.g.rs[r]=rs; }
      }
      __syncthreads();
    }

    f32x4 acc[2][2];
#pragma unroll
    for(int i=0;i<2;i++)
#pragma unroll
      for(int j=0;j<2;j++) acc[i][j] = (f32x4){0.f,0.f,0.f,0.f};

    for(int k0=0;k0<Ka;k0+=64){
      if(A16){
        *(short8*)&sm.g.As[ar][akq] = *(const short8*)(A16 + (size_t)(m0+ar)*Ka + k0 + akq);
      } else {
        const float* ap = Afp + (size_t)(m0+ar)*Ka + k0 + akq;
        float4 v0 = *(const float4*)ap, v1 = *(const float4*)(ap+4);
        float f[8] = {v0.x,v0.y,v0.z,v0.w,v1.x,v1.y,v1.z,v1.w};
        float mu = sm.g.mu[ar], rs = sm.g.rs[ar];
        int kb = k0 + akq;
#pragma unroll
        for(int i=0;i<8;i++) f[i] = (f[i]-mu)*rs*lng[kb+i] + lnb[kb+i];
        if(lnout && nt==0){
          float* dp = lnout + (size_t)(m0+ar)*DMODEL + kb;
          *(float4*)dp     = make_float4(f[0],f[1],f[2],f[3]);
          *(float4*)(dp+4) = make_float4(f[4],f[5],f[6],f[7]);
        }
        *(short8*)&sm.g.As[ar][akq] = pack8(f);
      }
      {
        const unsigned short* wp = Wsrc + (size_t)(nr0+br_)*Ka + k0 + bkq;
        *(short8*)&sm.g.Bs[br_][bkq]    = *(const short8*)wp;
        *(short8*)&sm.g.Bs[br_][bkq+8]  = *(const short8*)(wp+8);
        *(short8*)&sm.g.Bs[br_][bkq+16] = *(const short8*)(wp+16);
        *(short8*)&sm.g.Bs[br_][bkq+24] = *(const short8*)(wp+24);
      }
      __syncthreads();
      short8 af[2][2], bf[2][2];
#pragma unroll
      for(int kf=0;kf<2;kf++){
#pragma unroll
        for(int rt=0;rt<2;rt++) af[rt][kf] = *(const short8*)&sm.g.As[rt*16 + fr][kf*32 + fq];
#pragma unroll
        for(int ct=0;ct<2;ct++) bf[ct][kf] = *(const short8*)&sm.g.Bs[32*w + ct*16 + fr][kf*32 + fq];
      }
#pragma unroll
      for(int kf=0;kf<2;kf++)
#pragma unroll
        for(int rt=0;rt<2;rt++)
#pragma unroll
          for(int ct=0;ct<2;ct++)
            acc[rt][ct] = __builtin_amdgcn_mfma_f32_16x16x32_bf16(af[rt][kf], bf[ct][kf], acc[rt][ct], 0, 0, 0);
      __syncthreads();
    }

#pragma unroll
    for(int rt=0;rt<2;rt++){
#pragma unroll
      for(int ct=0;ct<2;ct++){
        int n = n0 + 32*w + ct*16 + fr;
#pragma unroll
        for(int r=0;r<4;r++){
          int row = m0 + rt*16 + (l>>4)*4 + r;
          float v = acc[rt][ct][r];
          if(bias)  v += bias[n];
          if(resid) v += resid[(size_t)row*DMODEL + n];
          if(act==1) v = gelu_t(v);
          if(cmode==0)      Cf[(size_t)row*c_rs + n] = v;
          else if(cmode==1) Cb[(size_t)row*c_rs + n] = f2b(v);
          else {
            int which = n>>9, rem = n&511;
            int b = row>>7, t = row&127;
            Cf[(size_t)which*(MROWS*DMODEL) +
               ((size_t)(b*NHEAD + (rem>>6))*SEQ + t)*DHEAD + (rem&63)] = v;
          }
        }
      }
    }
  }
}

// ---------------- attention stage (device fn): 128 tiles of (b,h,r0) ----------------
__device__ void attn_stage(const float* qb, const float* kb, const float* vb,
                           unsigned short* attb, SMem& sm){
  int tid = threadIdx.x;
  int d = tid&63, rr = tid>>6;
  for(int tile=blockIdx.x; tile<128; tile+=NWG){
    int b = tile>>5, h = (tile>>2)&7, r0 = (tile&3)*32;
    const float* Kh = kb + (size_t)(b*NHEAD+h)*SEQ*DHEAD;
    const float* Vh = vb + (size_t)(b*NHEAD+h)*SEQ*DHEAD;
    const float* Qh = qb + (size_t)(b*NHEAD+h)*SEQ*DHEAD;

    for(int k=rr;k<SEQ;k+=4) sm.a.kv[k][d ^ (k&60)] = Kh[k*DHEAD + d];
    for(int r=rr;r<32;r+=4)  sm.a.qs[r][d] = Qh[(size_t)(r0+r)*DHEAD + d];
    __syncthreads();

    { // logits
      int rp = tid>>4, kg = tid&15;
      float acc[2][8];
#pragma unroll
      for(int i=0;i<2;i++)
#pragma unroll
        for(int kk=0;kk<8;kk++) acc[i][kk]=0.f;
#pragma unroll 4
      for(int d4=0;d4<16;d4++){
        float4 q0 = *(const float4*)&sm.a.qs[2*rp][d4*4];
        float4 q1 = *(const float4*)&sm.a.qs[2*rp+1][d4*4];
#pragma unroll
        for(int kk=0;kk<8;kk++){
          int k = 8*kg + kk;
          int off = (d4*4) ^ (k&60);
          float4 kv4 = *(const float4*)&sm.a.kv[k][off];
          acc[0][kk] += q0.x*kv4.x + q0.y*kv4.y + q0.z*kv4.z + q0.w*kv4.w;
          acc[1][kk] += q1.x*kv4.x + q1.y*kv4.y + q1.z*kv4.z + q1.w*kv4.w;
        }
      }
#pragma unroll
      for(int i=0;i<2;i++){
        int t = r0 + 2*rp + i;
#pragma unroll
        for(int kk=0;kk<8;kk++){
          int k = 8*kg + kk;
          sm.a.wsm[2*rp+i][k] = (k > t) ? acc[i][kk]*0.125f : NEGF;
        }
      }
    }
    __syncthreads();

    { // softmax (all-masked row -> exact uniform 1/128, faithful to jnp)
      int l2 = tid&63, wv = tid>>6;
      for(int r=wv;r<32;r+=4){
        float l0 = sm.a.wsm[r][l2], l1 = sm.a.wsm[r][l2+64];
        float m = fmaxf(l0,l1);
#pragma unroll
        for(int off=32;off;off>>=1) m = fmaxf(m, __shfl_xor(m,off,64));
        float e0 = expf(l0-m), e1 = expf(l1-m);
        float s = e0+e1;
        s = wave_sum(s);
        float inv = 1.f/s;
        sm.a.wsm[r][l2] = e0*inv; sm.a.wsm[r][l2+64] = e1*inv;
      }
    }
    __syncthreads();

    for(int k=rr;k<SEQ;k+=4) sm.a.kv[k][d] = Vh[k*DHEAD + d];
    __syncthreads();

    { // out = w @ V, pack bf16
      int dq = (tid&15)*4, rg = tid>>4;
      for(int r=rg;r<32;r+=16){
        float4 a2 = make_float4(0.f,0.f,0.f,0.f);
        for(int k=0;k<SEQ;k++){
          float w0 = sm.a.wsm[r][k];
          float4 v = *(const float4*)&sm.a.kv[k][dq];
          a2.x += w0*v.x; a2.y += w0*v.y; a2.z += w0*v.z; a2.w += w0*v.w;
        }
        int row = b*SEQ + r0 + r;
        unsigned short* op = attb + (size_t)row*DMODEL + h*DHEAD + dq;
        op[0]=f2b(a2.x); op[1]=f2b(a2.y); op[2]=f2b(a2.z); op[3]=f2b(a2.w);
      }
    }
    __syncthreads();
  }
}

// ---------------- ctx stage (device fn): 64 tiles ----------------
__device__ float blk_sum(float v, float* scr){
  v = wave_sum(v);
  __syncthreads();
  if((threadIdx.x&63)==0) scr[threadIdx.x>>6]=v;
  __syncthreads();
  return scr[0]+scr[1]+scr[2]+scr[3];
}

__device__ void ctx_stage(const float* r2, const float* g2, const float* b2,
                          const float* Wr1, const float* cb1,
                          float* ctxt, int ptr, SMem& sm){
  int tid = threadIdx.x;
  for(int tile=blockIdx.x; tile<64; tile+=NWG){
    int b = tile>>4, j0 = (tile&15)*128;
    const float* rp = r2 + (size_t)(b*SEQ + ptr-1)*DMODEL;
    for(int k=tid;k<DMODEL;k+=256) sm.c.raw[k]=rp[k];
    __syncthreads();
    float s = 0.f;
    for(int k=tid;k<DMODEL;k+=256) s += sm.c.raw[k];
    s = blk_sum(s, sm.c.scr);
    float mu = s/(float)DMODEL;
    float v = 0.f;
    for(int k=tid;k<DMODEL;k+=256){ float d0 = sm.c.raw[k]-mu; v += d0*d0; }
    v = blk_sum(v, sm.c.scr);
    float rs = rsqrtf(v/(float)DMODEL + LN_EPS);
    for(int k=tid;k<DMODEL;k+=256) sm.c.ctx[k] = (sm.c.raw[k]-mu)*rs*g2[k] + b2[k];
    __syncthreads();
    int wv = tid>>6, l2 = tid&63;
    for(int jj=wv;jj<128;jj+=4){
      int j = j0+jj;
      const float* wp = Wr1 + (size_t)j*1024 + 512;
      float acc = 0.f;
#pragma unroll
      for(int q=0;q<8;q++){ int k = l2 + 64*q; acc += wp[k]*sm.c.ctx[k]; }
      acc = wave_sum(acc);
      if(l2==0) ctxt[b*DFFN + j] = acc + cb1[j];
    }
    __syncthreads();
  }
}

// ---------------- refine stage (device fn): wg 0..3 ----------------
__device__ void refine_stage(const float* M1, const float* ctxt,
                             const float* Wr2, const float* br2,
                             float* cur_x, const float* W_emb, const float* b_emb,
                             float* out, float* h0, unsigned short* h0b,
                             int s, int ptr, SMem& sm){
  if(blockIdx.x >= NB) return;
  int b = blockIdx.x, tid = threadIdx.x;
  if(tid < DIN) sm.r.cur[tid] = cur_x[b*DIN + tid];
  __syncthreads();
  for(int sub=0; sub<5; sub++){
    for(int jj=tid; jj<DFFN; jj+=256){
      float u = ctxt[b*DFFN + jj];
      const float* mp = M1 + (size_t)jj*DIN;
#pragma unroll
      for(int p=0;p<8;p++){
        float4 mv = *(const float4*)(mp + 4*p);
        u += mv.x*sm.r.cur[4*p] + mv.y*sm.r.cur[4*p+1] + mv.z*sm.r.cur[4*p+2] + mv.w*sm.r.cur[4*p+3];
      }
      sm.r.gs[jj] = gelu_t(u);
    }
    __syncthreads();
    int w = tid>>6, l = tid&63;
#pragma unroll
    for(int q=0;q<8;q++){
      int i = w*8 + q;
      const float* wr = Wr2 + (size_t)i*DFFN;
      float a = 0.f;
#pragma unroll
      for(int p=0;p<8;p++){
        int j0 = p*256 + l*4;
        float4 wv = *(const float4*)(wr + j0);
        float4 gv = *(const float4*)&sm.r.gs[j0];
        a += wv.x*gv.x + wv.y*gv.y + wv.z*gv.z + wv.w*gv.w;
      }
      a = wave_sum(a);
      if(l==0) sm.r.dscr[i] = a;
    }
    __syncthreads();
    if(tid < DIN) sm.r.cur[tid] += sm.r.dscr[tid] + br2[tid];
    __syncthreads();
  }
  if(tid < DIN){
    out[(b*NSTEP + s)*DIN + tid] = sm.r.cur[tid];
    cur_x[b*DIN + tid] = sm.r.cur[tid];
  }
  __syncthreads();
  for(int d=tid; d<DMODEL; d+=256){
    float s2 = 0.f;
#pragma unroll 8
    for(int i=0;i<DIN;i++) s2 += W_emb[d*DIN+i]*sm.r.cur[i];
    float v = SCALE_EMB*(s2 + b_emb[d]) + pe_val(ptr, d);
    size_t idx = (size_t)(b*SEQ + ptr)*DMODEL + d;
    h0[idx] = v;
    h0b[idx] = f2b(v);
  }
}

// ---------------- the persistent megakernel ----------------
__global__ __launch_bounds__(256) void mega(
    const float* __restrict__ ln1g, const float* __restrict__ ln1b,
    const float* __restrict__ ln2g, const float* __restrict__ ln2b,
    const float* __restrict__ b1, const float* __restrict__ b2v,
    const float* __restrict__ Wr1, const float* __restrict__ Wr2,
    const float* __restrict__ br2,
    const float* __restrict__ W_emb, const float* __restrict__ b_emb,
    const float* cb1, const float* M1, float* cur_x,
    float* h0, unsigned short* h0b, float* r2, float* hln,
    float* qb, unsigned short* attb, unsigned short* fb16,
    const unsigned short* W16, float* ctxt, float* out,
    unsigned* bar)
{
  __shared__ SMem sm;
  unsigned* cnt = bar;
  unsigned* gen = bar + 32;
  float* r1 = qb;              // alias: q dead when Wo writes
  float* hp = qb + 2*(size_t)MROWS*DMODEL;  // alias v: dead after attn
  const size_t BTD = (size_t)MROWS*DMODEL;

#pragma unroll 1
  for(int s=0;s<NSTEP;s++){
    int ptr = TH_ + s;
#pragma unroll 1
    for(int l=0;l<4;l++){
      const unsigned short* Wq16 = W16 + (size_t)l*262144;
      const unsigned short* Wk16 = W16 + 1048576 + (size_t)l*262144;
      const unsigned short* Wv16 = W16 + 2097152 + (size_t)l*262144;
      const unsigned short* Wo16 = W16 + 3145728 + (size_t)l*262144;
      const unsigned short* W116 = W16 + 4194304 + (size_t)l*1048576;
      const unsigned short* W216 = W16 + 8388608 + (size_t)l*1048576;

      // QKV (+LN2 prologue for l>0, writes hln)
      if(l==0)
        gemm_stage(12, h0b, nullptr,nullptr,nullptr,nullptr, DMODEL,
                   Wq16,Wk16,Wv16, nullptr,nullptr, qb,nullptr, 0, 2, 0, sm);
      else
        gemm_stage(12, nullptr, r2, ln2g+(l-1)*DMODEL, ln2b+(l-1)*DMODEL, hln, DMODEL,
                   Wq16,Wk16,Wv16, nullptr,nullptr, qb,nullptr, 0, 2, 0, sm);
      gbar(cnt,gen);

      attn_stage(qb, qb+BTD, qb+2*BTD, attb, sm);
      gbar(cnt,gen);

      // Wo + residual -> r1
      gemm_stage(4, attb, nullptr,nullptr,nullptr,nullptr, DMODEL,
                 Wo16,nullptr,nullptr, nullptr, (l==0)?h0:hln,
                 r1,nullptr, DMODEL, 0, 0, sm);
      gbar(cnt,gen);

      // FF1 (+LN1 prologue, writes hp): gelu -> fb16
      gemm_stage(16, nullptr, r1, ln1g+l*DMODEL, ln1b+l*DMODEL, hp, DMODEL,
                 W116,nullptr,nullptr, b1+l*DFFN, nullptr,
                 nullptr, fb16, DFFN, 1, 1, sm);
      gbar(cnt,gen);

      // FF2 + b2 + hp -> r2
      gemm_stage(4, fb16, nullptr,nullptr,nullptr,nullptr, DFFN,
                 W216,nullptr,nullptr, b2v+l*DMODEL, hp,
                 r2,nullptr, DMODEL, 0, 0, sm);
      gbar(cnt,gen);
    }

    ctx_stage(r2, ln2g+3*DMODEL, ln2b+3*DMODEL, Wr1, cb1, ctxt, ptr, sm);
    gbar(cnt,gen);

    refine_stage(M1, ctxt, Wr2, br2, cur_x, W_emb, b_emb, out, h0, h0b, s, ptr, sm);
    gbar(cnt,gen);
  }
}

// ---------------- host ----------------
extern "C" void kernel_launch(void* const* d_in, const int* in_sizes, int n_in,
                              void* d_out, int out_size, void* d_ws, size_t ws_size,
                              hipStream_t stream) {
  (void)in_sizes; (void)n_in; (void)out_size; (void)ws_size;
  const float* hist = (const float*)d_in[0];
  const float* W_emb= (const float*)d_in[2];
  const float* b_emb= (const float*)d_in[3];
  const float* Wq   = (const float*)d_in[4];
  const float* Wk   = (const float*)d_in[5];
  const float* Wv   = (const float*)d_in[6];
  const float* Wo   = (const float*)d_in[7];
  const float* ln1g = (const float*)d_in[8];
  const float* ln1b = (const float*)d_in[9];
  const float* W1   = (const float*)d_in[10];
  const float* b1   = (const float*)d_in[11];
  const float* W2   = (const float*)d_in[12];
  const float* b2v  = (const float*)d_in[13];
  const float* ln2g = (const float*)d_in[14];
  const float* ln2b = (const float*)d_in[15];
  const float* Wr1  = (const float*)d_in[16];
  const float* br1  = (const float*)d_in[17];
  const float* Wr2  = (const float*)d_in[18];
  const float* br2  = (const float*)d_in[19];
  float* out = (float*)d_out;
  float* ws  = (float*)d_ws;

  const size_t BTD = (size_t)MROWS*DMODEL;   // 262144 floats

  unsigned* bar = (unsigned*)ws;             // 256 B barrier block
  float* p = ws + 64;
  float* h0 = p;                      p += BTD;
  unsigned short* h0b = (unsigned short*)p; p += BTD/2;
  float* r2 = p;                      p += BTD;
  float* hln = p;                     p += BTD;
  float* qb = p;                      p += 3*BTD;   // q,k,v ; r1 aliases q, hp aliases v
  unsigned short* attb = (unsigned short*)p; p += BTD/2;
  unsigned short* fb16 = (unsigned short*)p; p += 2*BTD;
  unsigned short* W16 = (unsigned short*)p;  p += 6291456;
  float* M1 = p;                      p += (size_t)DFFN*DIN;
  float* cb1 = p;                     p += DFFN;
  float* ctxt = p;                    p += NB*DFFN;
  float* cur_x = p;                   p += NB*DIN;

  hipMemsetAsync(bar, 0, 256, stream);
  conv_w<<<dim3(6144),dim3(256),0,stream>>>(Wq,Wk,Wv,Wo,W1,W2,W16);
  init_h0<<<dim3(MROWS),dim3(256),0,stream>>>(hist,W_emb,b_emb,h0,h0b);
  init_misc<<<dim3(256),dim3(256),0,stream>>>(Wr1,W_emb,b_emb,br1,hist,M1,cb1,cur_x);

  mega<<<dim3(NWG),dim3(256),0,stream>>>(
      ln1g,ln1b,ln2g,ln2b,b1,b2v,Wr1,Wr2,br2,W_emb,b_emb,
      cb1,M1,cur_x,h0,h0b,r2,hln,qb,attb,fb16,W16,ctxt,out,bar);
}

// Round 5
// 4938.686 us; speedup vs baseline: 1.2514x; 1.2514x over previous
//
#include <hip/hip_runtime.h>
#include <math.h>

// ---------------- problem constants ----------------
namespace {
constexpr int NB = 4;
constexpr int SEQ = 128;
constexpr int TH_ = 120;
constexpr int NSTEP = 8;
constexpr int DMODEL = 512;
constexpr int NHEAD = 8;
constexpr int DHEAD = 64;
constexpr int DFFN = 2048;
constexpr int DIN = 32;
constexpr int MROWS = NB*SEQ;   // 512
constexpr float SCALE_EMB = 22.627416997969522f; // sqrt(512)
constexpr float LN_EPS = 1e-5f;
constexpr float NEGF = -3.4028234663852886e38f;  // jnp.finfo(f32).min
constexpr float PE_C = -0.017988946039015984f;   // -ln(10000)/512
constexpr int NWG = 256;        // persistent grid = #CUs
}

#define AG __HIP_MEMORY_SCOPE_AGENT
#define RLX __ATOMIC_RELAXED

using short8 = __attribute__((ext_vector_type(8))) short;
using f32x4  = __attribute__((ext_vector_type(4))) float;
typedef unsigned long long ull;

// ---------------- device-scope (LLC-coherent) access helpers ----------------
__device__ __forceinline__ ull ld64d(const void* p){
  return __hip_atomic_load((const ull*)p, RLX, AG);
}
__device__ __forceinline__ void st64d(void* p, ull v){
  __hip_atomic_store((ull*)p, v, RLX, AG);
}
__device__ __forceinline__ float ldf(const float* p){
  return __hip_atomic_load(p, RLX, AG);
}
__device__ __forceinline__ void stf(float* p, float v){
  __hip_atomic_store(p, v, RLX, AG);
}
__device__ __forceinline__ float2 ldf2(const float* p){
  union{ull u; float2 f;} c; c.u = ld64d(p); return c.f;
}
__device__ __forceinline__ void stf2(float* p, float2 f){
  union{ull u; float2 f;} c; c.f = f; st64d(p, c.u);
}
__device__ __forceinline__ void stb16(unsigned short* p, unsigned short v){
  asm volatile("global_store_short %0, %1, off sc0 sc1" :: "v"(p), "v"(v) : "memory");
}

// ---------------- generic helpers ----------------
__device__ __forceinline__ float wave_sum(float v){
#pragma unroll
  for(int off=32;off;off>>=1) v += __shfl_xor(v,off,64);
  return v;
}
__device__ __forceinline__ float gelu_t(float x){
  float t = 0.7978845608028654f*(x + 0.044715f*x*x*x);
  return 0.5f*x*(1.0f + tanhf(t));
}
__device__ __forceinline__ float pe_val(int t, int d){
  float div = expf((float)(d & ~1) * PE_C);
  float a = (float)t * div;
  return (d & 1) ? cosf(a) : sinf(a);
}
__device__ __forceinline__ unsigned short f2b(float f){
  union { float f; unsigned u; } c; c.f = f;
  unsigned u = c.u + 0x7FFFu + ((c.u>>16)&1u);
  return (unsigned short)(u>>16);
}
__device__ __forceinline__ short8 pack8(const float* f){
  short8 s;
#pragma unroll
  for(int i=0;i<8;i++) s[i] = (short)f2b(f[i]);
  return s;
}
__device__ __forceinline__ ull pack4u(float a, float b, float c, float d){
  return (ull)f2b(a) | ((ull)f2b(b)<<16) | ((ull)f2b(c)<<32) | ((ull)f2b(d)<<48);
}

// ---------------- shared-memory union ----------------
union SMem {
  struct {                                  // GEMM: 23 KB
    unsigned short As[32][72];
    unsigned short Bs[128][72];
  } g;
  struct {                                  // attention: 58.4 KB (max)
    float kv[SEQ][DHEAD];
    float wsm[32][132];
    float qs[32][68];
  } a;
  struct {                                  // ctx
    float raw[DMODEL]; float ctx[DMODEL]; float scr[4];
  } c;
  struct {                                  // refine: 17 KB
    float cur[DIN]; float dscr[DIN]; float gs[DFFN]; float ctx[DFFN];
  } r;
};

// ---------------- grid barrier: monotonic two-level, NO cache fences ----------------
// bar[0]=gen, bar[64]=root, bar[128+g*64]=group counters (separate cachelines)
__device__ __forceinline__ void gbar(unsigned* bar, unsigned n){
  __syncthreads();
  if(threadIdx.x==0){
    asm volatile("s_waitcnt vmcnt(0)" ::: "memory");  // drain sc-stores to LLC
    unsigned* grp = bar + 128 + ((blockIdx.x>>5)<<6);
    if(__hip_atomic_fetch_add(grp, 1u, RLX, AG) == n*32u - 1u){
      if(__hip_atomic_fetch_add(bar+64, 1u, RLX, AG) == n*8u - 1u){
        __hip_atomic_store(bar, n, RLX, AG);
      }
    }
    while(__hip_atomic_load(bar, RLX, AG) < n) __builtin_amdgcn_s_sleep(2);
    __atomic_signal_fence(__ATOMIC_ACQUIRE);
  }
  __syncthreads();
}

// ---------------- init kernels ----------------
__global__ __launch_bounds__(256) void conv_w(const float* __restrict__ Wq,
                                              const float* __restrict__ Wk,
                                              const float* __restrict__ Wv,
                                              const float* __restrict__ Wo,
                                              const float* __restrict__ W1,
                                              const float* __restrict__ W2,
                                              unsigned short* __restrict__ dst){
  size_t base = ((size_t)blockIdx.x*256 + threadIdx.x)*8;
  if(base >= 12582912u) return;
  const float* src; size_t off;
  if(base < 1048576u){ src=Wq; off=base; }
  else if(base < 2097152u){ src=Wk; off=base-1048576u; }
  else if(base < 3145728u){ src=Wv; off=base-2097152u; }
  else if(base < 4194304u){ src=Wo; off=base-3145728u; }
  else if(base < 8388608u){ src=W1; off=base-4194304u; }
  else { src=W2; off=base-8388608u; }
  float4 a = *(const float4*)(src+off);
  float4 b = *(const float4*)(src+off+4);
  float f[8] = {a.x,a.y,a.z,a.w,b.x,b.y,b.z,b.w};
  *(short8*)(dst + base) = pack8(f);
}

__global__ __launch_bounds__(256) void init_h0(const float* __restrict__ hist,
                                               const float* __restrict__ W_emb,
                                               const float* __restrict__ b_emb,
                                               float* __restrict__ h0,
                                               unsigned short* __restrict__ h0b){
  int bt = blockIdx.x;
  int b = bt >> 7, t = bt & 127;
  __shared__ float x[DIN];
  if(threadIdx.x < DIN)
    x[threadIdx.x] = (t < TH_) ? hist[((size_t)b*TH_ + t)*DIN + threadIdx.x] : 0.f;
  __syncthreads();
  for(int d = threadIdx.x; d < DMODEL; d += 256){
    float s = 0.f;
#pragma unroll 8
    for(int i=0;i<DIN;i++) s += W_emb[d*DIN+i]*x[i];
    float v = SCALE_EMB*(s + b_emb[d]) + pe_val(t,d);
    h0[(size_t)bt*DMODEL + d] = v;
    h0b[(size_t)bt*DMODEL + d] = f2b(v);
  }
}

__global__ __launch_bounds__(256) void init_misc(const float* __restrict__ Wr1,
                                                 const float* __restrict__ W_emb,
                                                 const float* __restrict__ b_emb,
                                                 const float* __restrict__ br1,
                                                 const float* __restrict__ hist,
                                                 float* __restrict__ M1,
                                                 float* __restrict__ cb1,
                                                 float* __restrict__ cur_x){
  __shared__ float row[DMODEL];
  int j0 = blockIdx.x*8;
  for(int jj=0;jj<8;jj++){
    int j = j0+jj;
    for(int k=threadIdx.x;k<DMODEL;k+=256) row[k] = Wr1[(size_t)j*1024 + k];
    __syncthreads();
    if(threadIdx.x < DIN){
      int i = threadIdx.x; float s = 0.f;
      for(int k=0;k<DMODEL;k++) s += row[k]*W_emb[k*DIN+i];
      M1[j*DIN+i] = SCALE_EMB*s;
    } else if(threadIdx.x == DIN){
      float s=0.f;
      for(int k=0;k<DMODEL;k++) s += row[k]*b_emb[k];
      cb1[j] = br1[j] + SCALE_EMB*s;
    }
    __syncthreads();
  }
  if(blockIdx.x==0 && threadIdx.x<NB*DIN){
    int b = threadIdx.x>>5, i = threadIdx.x&31;
    cur_x[b*DIN+i] = hist[((size_t)b*TH_ + (TH_-1))*DIN + i];
  }
}

// ---------------- LN stage: one wave per row; fp32(sc) + bf16(sc) outputs -------------
__device__ void ln_stage(const float* X, const float* g, const float* bta,
                         float* Y, unsigned short* Yb){
  if(blockIdx.x >= 128) return;
  int w = threadIdx.x>>6, l = threadIdx.x&63;
  int row = blockIdx.x*4 + w;
  const float* xp = X + (size_t)row*DMODEL + l*8;
  float f[8];
  float2 t0=ldf2(xp), t1=ldf2(xp+2), t2=ldf2(xp+4), t3=ldf2(xp+6);
  f[0]=t0.x;f[1]=t0.y;f[2]=t1.x;f[3]=t1.y;f[4]=t2.x;f[5]=t2.y;f[6]=t3.x;f[7]=t3.y;
  float s = 0.f;
#pragma unroll
  for(int i=0;i<8;i++) s += f[i];
  s = wave_sum(s);
  float mu = s*(1.f/DMODEL);
  float v = 0.f;
#pragma unroll
  for(int i=0;i<8;i++){ float d0=f[i]-mu; v += d0*d0; }
  v = wave_sum(v);
  float rs = rsqrtf(v*(1.f/DMODEL) + LN_EPS);
#pragma unroll
  for(int i=0;i<8;i++){
    int c = l*8+i;
    f[i] = (f[i]-mu)*rs*g[c] + bta[c];
  }
  float* yp = Y + (size_t)row*DMODEL + l*8;
  stf2(yp,   make_float2(f[0],f[1]));
  stf2(yp+2, make_float2(f[2],f[3]));
  stf2(yp+4, make_float2(f[4],f[5]));
  stf2(yp+6, make_float2(f[6],f[7]));
  unsigned short* bp = Yb + (size_t)row*DMODEL + l*8;
  st64d(bp,   pack4u(f[0],f[1],f[2],f[3]));
  st64d(bp+4, pack4u(f[4],f[5],f[6],f[7]));
}

// ---------------- GEMM stage: 32x128 tiles, bf16 MFMA, reg-prefetch K-loop -------------
// A via sc-loads (bf16); W via cached loads (L2-resident).
// cmode: 0 fp32 out (+bias,+resid sc); 1 bf16 out (+bias,+act); 2 fused-QKV scatter fp32.
__device__ void gemm_stage(
    int ntN,
    const unsigned short* A16, int Ka,
    const unsigned short* W0, const unsigned short* W1w, const unsigned short* W2w,
    const float* bias, const float* resid,
    float* Cf, unsigned short* Cb, int c_rs, int cmode, int act,
    SMem& sm)
{
  int tid = threadIdx.x, w = tid>>6, l = tid&63;
  int ntiles = 16*ntN;
  int fr = l&15, fq = (l>>4)*8;
  int ar = tid>>3, akq = (tid&7)*8;
  int br_ = tid>>1, bkq = (tid&1)*32;

  for(int tile=blockIdx.x; tile<ntiles; tile+=NWG){
    int mt = tile/ntN, nt = tile - mt*ntN;
    int m0 = mt*32, n0 = nt*128;
    const unsigned short* Wsrc; int nr0;
    if(cmode==2){ int which = n0>>9; Wsrc = (which==0?W0:(which==1?W1w:W2w)); nr0 = n0&511; }
    else { Wsrc = W0; nr0 = n0; }

    f32x4 acc[2][2];
#pragma unroll
    for(int i=0;i<2;i++)
#pragma unroll
      for(int j=0;j<2;j++) acc[i][j] = (f32x4){0.f,0.f,0.f,0.f};

    const unsigned short* arow = A16 + (size_t)(m0+ar)*Ka + akq;
    const unsigned short* brow = Wsrc + (size_t)(nr0+br_)*Ka + bkq;
    // prefetch chunk 0
    ull a0 = ld64d(arow), a1 = ld64d(arow+4);
    short8 b0 = *(const short8*)brow;
    short8 b1 = *(const short8*)(brow+8);
    short8 b2 = *(const short8*)(brow+16);
    short8 b3 = *(const short8*)(brow+24);

    for(int k0=0;k0<Ka;k0+=64){
      *(ull*)&sm.g.As[ar][akq]   = a0;
      *(ull*)&sm.g.As[ar][akq+4] = a1;
      *(short8*)&sm.g.Bs[br_][bkq]    = b0;
      *(short8*)&sm.g.Bs[br_][bkq+8]  = b1;
      *(short8*)&sm.g.Bs[br_][bkq+16] = b2;
      *(short8*)&sm.g.Bs[br_][bkq+24] = b3;
      __syncthreads();
      if(k0+64 < Ka){   // prefetch next chunk while MFMAs run
        a0 = ld64d(arow + k0+64);
        a1 = ld64d(arow + k0+64 + 4);
        const unsigned short* bp = brow + k0+64;
        b0 = *(const short8*)bp;
        b1 = *(const short8*)(bp+8);
        b2 = *(const short8*)(bp+16);
        b3 = *(const short8*)(bp+24);
      }
      short8 af[2][2], bf[2][2];
#pragma unroll
      for(int kf=0;kf<2;kf++){
#pragma unroll
        for(int rt=0;rt<2;rt++) af[rt][kf] = *(const short8*)&sm.g.As[rt*16 + fr][kf*32 + fq];
#pragma unroll
        for(int ct=0;ct<2;ct++) bf[ct][kf] = *(const short8*)&sm.g.Bs[32*w + ct*16 + fr][kf*32 + fq];
      }
#pragma unroll
      for(int kf=0;kf<2;kf++)
#pragma unroll
        for(int rt=0;rt<2;rt++)
#pragma unroll
          for(int ct=0;ct<2;ct++)
            acc[rt][ct] = __builtin_amdgcn_mfma_f32_16x16x32_bf16(af[rt][kf], bf[ct][kf], acc[rt][ct], 0, 0, 0);
      __syncthreads();
    }

#pragma unroll
    for(int rt=0;rt<2;rt++){
#pragma unroll
      for(int ct=0;ct<2;ct++){
        int n = n0 + 32*w + ct*16 + fr;
#pragma unroll
        for(int r=0;r<4;r++){
          int row = m0 + rt*16 + (l>>4)*4 + r;
          float v = acc[rt][ct][r];
          if(bias)  v += bias[n];
          if(resid) v += ldf(resid + (size_t)row*DMODEL + n);
          if(act==1) v = gelu_t(v);
          if(cmode==0)      stf(Cf + (size_t)row*c_rs + n, v);
          else if(cmode==1) stb16(Cb + (size_t)row*c_rs + n, f2b(v));
          else {
            int which = n>>9, rem = n&511;
            int b = row>>7, t = row&127;
            stf(Cf + (size_t)which*(MROWS*DMODEL) +
                ((size_t)(b*NHEAD + (rem>>6))*SEQ + t)*DHEAD + (rem&63), v);
          }
        }
      }
    }
  }
}

// ---------------- attention stage: 128 tiles of (b,h,r0) ----------------
__device__ void attn_stage(const float* qb, const float* kb, const float* vb,
                           unsigned short* attb, SMem& sm){
  int tid = threadIdx.x;
  int d = tid&63, rr = tid>>6;
  for(int tile=blockIdx.x; tile<128; tile+=NWG){
    int b = tile>>5, h = (tile>>2)&7, r0 = (tile&3)*32;
    const float* Kh = kb + (size_t)(b*NHEAD+h)*SEQ*DHEAD;
    const float* Vh = vb + (size_t)(b*NHEAD+h)*SEQ*DHEAD;
    const float* Qh = qb + (size_t)(b*NHEAD+h)*SEQ*DHEAD;

    for(int k=rr;k<SEQ;k+=4) sm.a.kv[k][d ^ (k&60)] = ldf(Kh + k*DHEAD + d);
    for(int r=rr;r<32;r+=4)  sm.a.qs[r][d] = ldf(Qh + (size_t)(r0+r)*DHEAD + d);
    __syncthreads();

    { // logits
      int rp = tid>>4, kg = tid&15;
      float acc[2][8];
#pragma unroll
      for(int i=0;i<2;i++)
#pragma unroll
        for(int kk=0;kk<8;kk++) acc[i][kk]=0.f;
#pragma unroll 4
      for(int d4=0;d4<16;d4++){
        float4 q0 = *(const float4*)&sm.a.qs[2*rp][d4*4];
        float4 q1 = *(const float4*)&sm.a.qs[2*rp+1][d4*4];
#pragma unroll
        for(int kk=0;kk<8;kk++){
          int k = 8*kg + kk;
          int off = (d4*4) ^ (k&60);
          float4 kv4 = *(const float4*)&sm.a.kv[k][off];
          acc[0][kk] += q0.x*kv4.x + q0.y*kv4.y + q0.z*kv4.z + q0.w*kv4.w;
          acc[1][kk] += q1.x*kv4.x + q1.y*kv4.y + q1.z*kv4.z + q1.w*kv4.w;
        }
      }
#pragma unroll
      for(int i=0;i<2;i++){
        int t = r0 + 2*rp + i;
#pragma unroll
        for(int kk=0;kk<8;kk++){
          int k = 8*kg + kk;
          sm.a.wsm[2*rp+i][k] = (k > t) ? acc[i][kk]*0.125f : NEGF;
        }
      }
    }
    __syncthreads();

    { // softmax (all-masked row -> exact uniform 1/128, faithful to jnp)
      int l2 = tid&63, wv = tid>>6;
      for(int r=wv;r<32;r+=4){
        float l0 = sm.a.wsm[r][l2], l1 = sm.a.wsm[r][l2+64];
        float m = fmaxf(l0,l1);
#pragma unroll
        for(int off=32;off;off>>=1) m = fmaxf(m, __shfl_xor(m,off,64));
        float e0 = expf(l0-m), e1 = expf(l1-m);
        float s = e0+e1;
        s = wave_sum(s);
        float inv = 1.f/s;
        sm.a.wsm[r][l2] = e0*inv; sm.a.wsm[r][l2+64] = e1*inv;
      }
    }
    __syncthreads();

    for(int k=rr;k<SEQ;k+=4) sm.a.kv[k][d] = ldf(Vh + k*DHEAD + d);
    __syncthreads();

    { // out = w @ V, pack bf16 (4 at a time -> 8B sc store)
      int dq = (tid&15)*4, rg = tid>>4;
      for(int r=rg;r<32;r+=16){
        float4 a2 = make_float4(0.f,0.f,0.f,0.f);
        for(int k=0;k<SEQ;k++){
          float w0 = sm.a.wsm[r][k];
          float4 v = *(const float4*)&sm.a.kv[k][dq];
          a2.x += w0*v.x; a2.y += w0*v.y; a2.z += w0*v.z; a2.w += w0*v.w;
        }
        int row = b*SEQ + r0 + r;
        st64d(attb + (size_t)row*DMODEL + h*DHEAD + dq, pack4u(a2.x,a2.y,a2.z,a2.w));
      }
    }
    __syncthreads();
  }
}

// ---------------- ctx stage: 64 tiles ----------------
__device__ float blk_sum(float v, float* scr){
  v = wave_sum(v);
  __syncthreads();
  if((threadIdx.x&63)==0) scr[threadIdx.x>>6]=v;
  __syncthreads();
  return scr[0]+scr[1]+scr[2]+scr[3];
}

__device__ void ctx_stage(const float* r2, const float* g2, const float* b2,
                          const float* Wr1, const float* cb1,
                          float* ctxt, int ptr, SMem& sm){
  int tid = threadIdx.x;
  for(int tile=blockIdx.x; tile<64; tile+=NWG){
    int b = tile>>4, j0 = (tile&15)*128;
    const float* rp = r2 + (size_t)(b*SEQ + ptr-1)*DMODEL;
    for(int k=tid;k<DMODEL;k+=256) sm.c.raw[k]=ldf(rp+k);
    __syncthreads();
    float s = 0.f;
    for(int k=tid;k<DMODEL;k+=256) s += sm.c.raw[k];
    s = blk_sum(s, sm.c.scr);
    float mu = s/(float)DMODEL;
    float v = 0.f;
    for(int k=tid;k<DMODEL;k+=256){ float d0 = sm.c.raw[k]-mu; v += d0*d0; }
    v = blk_sum(v, sm.c.scr);
    float rs = rsqrtf(v/(float)DMODEL + LN_EPS);
    for(int k=tid;k<DMODEL;k+=256) sm.c.ctx[k] = (sm.c.raw[k]-mu)*rs*g2[k] + b2[k];
    __syncthreads();
    int wv = tid>>6, l2 = tid&63;
    for(int jj=wv;jj<128;jj+=4){
      int j = j0+jj;
      const float* wp = Wr1 + (size_t)j*1024 + 512;
      float acc = 0.f;
#pragma unroll
      for(int q=0;q<8;q++){ int k = l2 + 64*q; acc += wp[k]*sm.c.ctx[k]; }
      acc = wave_sum(acc);
      if(l2==0) stf(ctxt + b*DFFN + j, acc + cb1[j]);
    }
    __syncthreads();
  }
}

// ---------------- refine stage: wg 0..3 ----------------
__device__ void refine_stage(const float* M1, const float* ctxt,
                             const float* Wr2, const float* br2,
                             float* cur_x, const float* W_emb, const float* b_emb,
                             float* out, float* h0, unsigned short* h0b,
                             int s, int ptr, SMem& sm){
  if(blockIdx.x >= NB) return;
  int b = blockIdx.x, tid = threadIdx.x;
  if(tid < DIN) sm.r.cur[tid] = ldf(cur_x + b*DIN + tid);
  for(int jj=tid; jj<DFFN; jj+=256) sm.r.ctx[jj] = ldf(ctxt + b*DFFN + jj);
  __syncthreads();
  for(int sub=0; sub<5; sub++){
    for(int jj=tid; jj<DFFN; jj+=256){
      float u = sm.r.ctx[jj];
      const float* mp = M1 + (size_t)jj*DIN;
#pragma unroll
      for(int p=0;p<8;p++){
        float4 mv = *(const float4*)(mp + 4*p);
        u += mv.x*sm.r.cur[4*p] + mv.y*sm.r.cur[4*p+1] + mv.z*sm.r.cur[4*p+2] + mv.w*sm.r.cur[4*p+3];
      }
      sm.r.gs[jj] = gelu_t(u);
    }
    __syncthreads();
    int w = tid>>6, l = tid&63;
#pragma unroll
    for(int q=0;q<8;q++){
      int i = w*8 + q;
      const float* wr = Wr2 + (size_t)i*DFFN;
      float a = 0.f;
#pragma unroll
      for(int p=0;p<8;p++){
        int j0 = p*256 + l*4;
        float4 wv = *(const float4*)(wr + j0);
        float4 gv = *(const float4*)&sm.r.gs[j0];
        a += wv.x*gv.x + wv.y*gv.y + wv.z*gv.z + wv.w*gv.w;
      }
      a = wave_sum(a);
      if(l==0) sm.r.dscr[i] = a;
    }
    __syncthreads();
    if(tid < DIN) sm.r.cur[tid] += sm.r.dscr[tid] + br2[tid];
    __syncthreads();
  }
  if(tid < DIN){
    stf(out + (b*NSTEP + s)*DIN + tid, sm.r.cur[tid]);
    stf(cur_x + b*DIN + tid, sm.r.cur[tid]);
  }
  __syncthreads();
  for(int d=tid; d<DMODEL; d+=256){
    float s2 = 0.f;
#pragma unroll 8
    for(int i=0;i<DIN;i++) s2 += W_emb[d*DIN+i]*sm.r.cur[i];
    float v = SCALE_EMB*(s2 + b_emb[d]) + pe_val(ptr, d);
    size_t idx = (size_t)(b*SEQ + ptr)*DMODEL + d;
    stf(h0 + idx, v);
    stb16(h0b + idx, f2b(v));
  }
}

// ---------------- the persistent megakernel ----------------
__global__ __launch_bounds__(256) void mega(
    const float* __restrict__ ln1g, const float* __restrict__ ln1b,
    const float* __restrict__ ln2g, const float* __restrict__ ln2b,
    const float* __restrict__ b1, const float* __restrict__ b2v,
    const float* __restrict__ Wr1, const float* __restrict__ Wr2,
    const float* __restrict__ br2,
    const float* __restrict__ W_emb, const float* __restrict__ b_emb,
    const float* cb1, const float* M1, float* cur_x,
    float* h0, unsigned short* h0b, float* r2,
    float* hln, unsigned short* hlnb,
    float* qb, unsigned short* attb, unsigned short* fb16,
    const unsigned short* W16, float* ctxt, float* out,
    unsigned* bar)
{
  __shared__ SMem sm;
  const size_t BTD = (size_t)MROWS*DMODEL;
  float* kb = qb + BTD;
  float* vb = qb + 2*BTD;
  float* r1 = qb;                       // alias: q dead once Wo runs
  float* hp = kb;                       // alias: k dead once LN1 runs
  unsigned short* hpb = (unsigned short*)vb;  // alias: v dead once LN1 runs
  unsigned bi = 0;

#pragma unroll 1
  for(int s=0;s<NSTEP;s++){
    int ptr = TH_ + s;
#pragma unroll 1
    for(int l=0;l<4;l++){
      const unsigned short* Wq16 = W16 + (size_t)l*262144;
      const unsigned short* Wk16 = W16 + 1048576 + (size_t)l*262144;
      const unsigned short* Wv16 = W16 + 2097152 + (size_t)l*262144;
      const unsigned short* Wo16 = W16 + 3145728 + (size_t)l*262144;
      const unsigned short* W116 = W16 + 4194304 + (size_t)l*1048576;
      const unsigned short* W216 = W16 + 8388608 + (size_t)l*1048576;

      if(l>0){
        ln_stage(r2, ln2g+(l-1)*DMODEL, ln2b+(l-1)*DMODEL, hln, hlnb);
        gbar(bar,++bi);
      }
      // fused QKV
      gemm_stage(12, (l==0)? h0b : hlnb, DMODEL,
                 Wq16,Wk16,Wv16, nullptr,nullptr, qb,nullptr, 0, 2, 0, sm);
      gbar(bar,++bi);

      attn_stage(qb, kb, vb, attb, sm);
      gbar(bar,++bi);

      // Wo + residual -> r1
      gemm_stage(4, attb, DMODEL, Wo16,nullptr,nullptr,
                 nullptr, (l==0)?h0:hln, r1,nullptr, DMODEL, 0, 0, sm);
      gbar(bar,++bi);

      ln_stage(r1, ln1g+l*DMODEL, ln1b+l*DMODEL, hp, hpb);
      gbar(bar,++bi);

      // FF1: gelu -> fb16
      gemm_stage(16, hpb, DMODEL, W116,nullptr,nullptr,
                 b1+l*DFFN, nullptr, nullptr, fb16, DFFN, 1, 1, sm);
      gbar(bar,++bi);

      // FF2 + b2 + hp -> r2
      gemm_stage(4, fb16, DFFN, W216,nullptr,nullptr,
                 b2v+l*DMODEL, hp, r2,nullptr, DMODEL, 0, 0, sm);
      gbar(bar,++bi);
    }

    ctx_stage(r2, ln2g+3*DMODEL, ln2b+3*DMODEL, Wr1, cb1, ctxt, ptr, sm);
    gbar(bar,++bi);

    refine_stage(M1, ctxt, Wr2, br2, cur_x, W_emb, b_emb, out, h0, h0b, s, ptr, sm);
    gbar(bar,++bi);
  }
}

// ---------------- host ----------------
extern "C" void kernel_launch(void* const* d_in, const int* in_sizes, int n_in,
                              void* d_out, int out_size, void* d_ws, size_t ws_size,
                              hipStream_t stream) {
  (void)in_sizes; (void)n_in; (void)out_size; (void)ws_size;
  const float* hist = (const float*)d_in[0];
  const float* W_emb= (const float*)d_in[2];
  const float* b_emb= (const float*)d_in[3];
  const float* Wq   = (const float*)d_in[4];
  const float* Wk   = (const float*)d_in[5];
  const float* Wv   = (const float*)d_in[6];
  const float* Wo   = (const float*)d_in[7];
  const float* ln1g = (const float*)d_in[8];
  const float* ln1b = (const float*)d_in[9];
  const float* W1   = (const float*)d_in[10];
  const float* b1   = (const float*)d_in[11];
  const float* W2   = (const float*)d_in[12];
  const float* b2v  = (const float*)d_in[13];
  const float* ln2g = (const float*)d_in[14];
  const float* ln2b = (const float*)d_in[15];
  const float* Wr1  = (const float*)d_in[16];
  const float* br1  = (const float*)d_in[17];
  const float* Wr2  = (const float*)d_in[18];
  const float* br2  = (const float*)d_in[19];
  float* out = (float*)d_out;
  float* ws  = (float*)d_ws;

  const size_t BTD = (size_t)MROWS*DMODEL;   // 262144 floats

  unsigned* bar = (unsigned*)ws;             // 4 KB barrier block
  float* p = ws + 1024;
  float* h0 = p;                             p += BTD;
  unsigned short* h0b = (unsigned short*)p;  p += BTD/2;
  float* r2 = p;                             p += BTD;
  float* hln = p;                            p += BTD;
  unsigned short* hlnb = (unsigned short*)p; p += BTD/2;
  float* qb = p;                             p += 3*BTD;  // q,k,v; r1=q, hp=k, hpb=v
  unsigned short* attb = (unsigned short*)p; p += BTD/2;
  unsigned short* fb16 = (unsigned short*)p; p += 2*BTD;
  unsigned short* W16 = (unsigned short*)p;  p += 6291456;
  float* M1 = p;                             p += (size_t)DFFN*DIN;
  float* cb1 = p;                            p += DFFN;
  float* ctxt = p;                           p += NB*DFFN;
  float* cur_x = p;                          p += NB*DIN;

  hipMemsetAsync(bar, 0, 4096, stream);
  conv_w<<<dim3(6144),dim3(256),0,stream>>>(Wq,Wk,Wv,Wo,W1,W2,W16);
  init_h0<<<dim3(MROWS),dim3(256),0,stream>>>(hist,W_emb,b_emb,h0,h0b);
  init_misc<<<dim3(256),dim3(256),0,stream>>>(Wr1,W_emb,b_emb,br1,hist,M1,cb1,cur_x);

  mega<<<dim3(NWG),dim3(256),0,stream>>>(
      ln1g,ln1b,ln2g,ln2b,b1,b2v,Wr1,Wr2,br2,W_emb,b_emb,
      cb1,M1,cur_x,h0,h0b,r2,hln,hlnb,qb,attb,fb16,W16,ctxt,out,bar);
}